// Round 11
// baseline (953.194 us; speedup 1.0000x reference)
//
#include <hip/hip_runtime.h>
#include <hip/hip_bf16.h>

// Problem constants (static per reference)
#define NTOK 16384   // B*T
#define HD   512     // H
#define ED   8       // E experts
#define FD   2048    // F
#define CAP  5120    // capacity per expert
#define NA   32768   // NTOK * K(=2)

typedef __bf16 bf16x8 __attribute__((ext_vector_type(8)));
typedef float  f32x4  __attribute__((ext_vector_type(4)));

// Workspace layout (bytes). Total ~249 MB.
static constexpr size_t OFF_EIDX = 0;                                  // int[NA]
static constexpr size_t OFF_WGT  = 131072;                             // float[NA]
static constexpr size_t OFF_STOK = 262144;                             // int[ED*CAP]
static constexpr size_t OFF_ASLOT= 425984;                             // int[NA]
static constexpr size_t OFF_ECNT = 557056;                             // int[ED]
static constexpr size_t OFF_W2T  = 1u << 20;                           // bf16[ED][HD][FD]
static constexpr size_t OFF_H    = OFF_W2T + (size_t)ED*HD*FD*2;       // bf16[ED][CAP][FD]
static constexpr size_t OFF_W1T  = OFF_H   + (size_t)ED*CAP*FD*2;      // bf16[ED][FD][HD]
static constexpr size_t OFF_XBF  = OFF_W1T + (size_t)ED*FD*HD*2;       // bf16[NTOK][HD]
static constexpr size_t OFF_EOUT = OFF_XBF + (size_t)NTOK*HD*2;        // fp16[ED][CAP][HD]

__device__ __forceinline__ unsigned short f2bf(float f) {
    __bf16 b = (__bf16)f;
    return __builtin_bit_cast(unsigned short, b);
}
__device__ __forceinline__ unsigned short f2h(float f) {
    _Float16 h = (_Float16)f;
    return __builtin_bit_cast(unsigned short, h);
}
__device__ __forceinline__ float h2f(unsigned short u) {
    return (float)__builtin_bit_cast(_Float16, u);
}

// gelu(tanh approx) == v * sigmoid(2*0.79788456*(v + 0.044715 v^3))
// rcp (~1ulp) instead of exact div: invisible after bf16 rounding (R2).
__device__ __forceinline__ float gelu_fast(float v) {
    const float t = v * v;
    const float u = v * fmaf(t, 0.0713548214f, 1.5957691216f);
    const float e = __expf(-u);
    return v * __builtin_amdgcn_rcpf(1.f + e);
}

// ---------------------------------------------------------------------------
// Fused weight transposes: z<ED -> w1 [HD][FD] -> w1t [FD][HD];
//                          z>=ED -> w2 [FD][HD] -> w2t [HD][FD].
// ---------------------------------------------------------------------------
__global__ __launch_bounds__(256) void transpose_cast_kernel(
    const float* __restrict__ w1, unsigned short* __restrict__ w1t,
    const float* __restrict__ w2, unsigned short* __restrict__ w2t)
{
    __shared__ unsigned short tile[32][33];
    const int z = blockIdx.z;
    const bool is1 = z < ED;
    const int e = is1 ? z : z - ED;
    const int R = is1 ? HD : FD;
    const int C = is1 ? FD : HD;
    if (blockIdx.x * 32 >= C || blockIdx.y * 32 >= R) return;
    const float* in = (is1 ? w1 : w2) + (size_t)e * HD * FD;
    unsigned short* out = (is1 ? w1t : w2t) + (size_t)e * HD * FD;
    const int r0 = blockIdx.y * 32, c0 = blockIdx.x * 32;
    const int tr = threadIdx.x >> 3, tc = (threadIdx.x & 7) * 4;
    const float4 v = *(const float4*)(in + (size_t)(r0 + tr) * C + c0 + tc);
    tile[tr][tc + 0] = f2bf(v.x);
    tile[tr][tc + 1] = f2bf(v.y);
    tile[tr][tc + 2] = f2bf(v.z);
    tile[tr][tc + 3] = f2bf(v.w);
    __syncthreads();
    ushort4 o;
    o.x = tile[tc + 0][tr]; o.y = tile[tc + 1][tr];
    o.z = tile[tc + 2][tr]; o.w = tile[tc + 3][tr];
    *(ushort4*)(out + (size_t)(c0 + tr) * R + r0 + tc) = o;
}

// ---------------------------------------------------------------------------
// Router (+ fused x->bf16 cast)
// ---------------------------------------------------------------------------
__global__ __launch_bounds__(256) void router_kernel(
    const float* __restrict__ x, const float* __restrict__ rw,
    int* __restrict__ eidx, float* __restrict__ wgt,
    unsigned short* __restrict__ xbf)
{
    __shared__ float rws[HD * ED];
    const int tid = threadIdx.x;
    for (int i = tid * 4; i < HD * ED; i += 256 * 4)
        *(float4*)(rws + i) = *(const float4*)(rw + i);
    __syncthreads();

    const int wid = tid >> 6, lane = tid & 63;
    const int t = blockIdx.x * 4 + wid;
    const float* xr = x + (size_t)t * HD;

    float acc[ED];
#pragma unroll
    for (int e = 0; e < ED; e++) acc[e] = 0.f;

    float4 xv0 = *(const float4*)(xr + lane * 8);
    float4 xv1 = *(const float4*)(xr + lane * 8 + 4);
    float xv[8] = {xv0.x, xv0.y, xv0.z, xv0.w, xv1.x, xv1.y, xv1.z, xv1.w};

    union { unsigned short us[8]; uint4 v; } pk;
#pragma unroll
    for (int j = 0; j < 8; j++) pk.us[j] = f2bf(xv[j]);
    *(uint4*)(xbf + (size_t)t * HD + lane * 8) = pk.v;

#pragma unroll
    for (int j = 0; j < 8; j++) {
        const int h = lane * 8 + j;
#pragma unroll
        for (int e = 0; e < ED; e++) acc[e] += xv[j] * rws[h * ED + e];
    }
#pragma unroll
    for (int off = 32; off >= 1; off >>= 1) {
#pragma unroll
        for (int e = 0; e < ED; e++) acc[e] += __shfl_down(acc[e], off);
    }
    if (lane == 0) {
        int e0 = 0; float l0 = acc[0];
        for (int e = 1; e < ED; e++) if (acc[e] > l0) { l0 = acc[e]; e0 = e; }
        int e1 = 0; float l1 = -1e30f;
        for (int e = 0; e < ED; e++) {
            if (e == e0) continue;
            if (acc[e] > l1) { l1 = acc[e]; e1 = e; }
        }
        const float ex = expf(l1 - l0);
        const float inv = 1.f / (1.f + ex);
        eidx[t * 2 + 0] = e0;  eidx[t * 2 + 1] = e1;
        wgt [t * 2 + 0] = inv; wgt [t * 2 + 1] = ex * inv;
    }
}

// ---------------------------------------------------------------------------
// Deterministic slot assignment (stable-sort-by-expert), parallel 3-pass scan.
// ---------------------------------------------------------------------------
__global__ __launch_bounds__(1024) void scan_kernel(
    const int* __restrict__ eidx,
    int* __restrict__ stok, int* __restrict__ aslot, int* __restrict__ ecnt)
{
    __shared__ int wcnt[32][16][ED];
    __shared__ int woff[32][16][ED];
    const int tid = threadIdx.x;
    const int lane = tid & 63, wid = tid >> 6;
    const unsigned long long below = (1ull << lane) - 1ull;

    for (int i = tid; i < ED * CAP; i += 1024) stok[i] = -1;

    for (int c = 0; c < NA / 1024; c++) {
        const int e = eidx[c * 1024 + tid];
#pragma unroll
        for (int ee = 0; ee < ED; ee++) {
            unsigned long long m = __ballot(e == ee);
            if (lane == 0) wcnt[c][wid][ee] = __popcll(m);
        }
    }
    __syncthreads();

    if (wid < ED) {
        const int e = wid;
        int carry = 0;
#pragma unroll
        for (int r = 0; r < 8; r++) {
            const int idx = r * 64 + lane;
            const int v = wcnt[idx >> 4][idx & 15][e];
            int s = v;
#pragma unroll
            for (int off = 1; off < 64; off <<= 1) {
                int u = __shfl_up(s, off);
                if (lane >= off) s += u;
            }
            woff[idx >> 4][idx & 15][e] = carry + s - v;
            carry += __shfl(s, 63);
        }
        if (lane == 0) ecnt[e] = carry < CAP ? carry : CAP;
    }
    __syncthreads();

    for (int c = 0; c < NA / 1024; c++) {
        const int a = c * 1024 + tid;
        const int e = eidx[a];
        int myrank = 0;
#pragma unroll
        for (int ee = 0; ee < ED; ee++) {
            unsigned long long m = __ballot(e == ee);
            if (ee == e) myrank = __popcll(m & below);
        }
        const int slot = woff[c][wid][e] + myrank;
        if (slot < CAP) {
            stok[e * CAP + slot] = a >> 1;
            aslot[a] = slot;
        } else {
            aslot[a] = -1;
        }
    }
}

// ---------------------------------------------------------------------------
// MFMA GEMM, R11: 256x128 block tile, 4 waves, wave tile 128x64 — register-
// budget-fixed. R10 post-mortem: acc[8][4]=128 AGPR + 144 arch VGPR = 272
// unified > 256 -> 1 wave/SIMD -> occupancy 8%, MfmaUtil 7.6 (latency naked).
// Fixes: (a) COMPUTE split into two half-phases reusing af[4] (peak frags
// 32 not 48); (b) __launch_bounds__(256, 2) pins the allocator at the 256-reg
// budget -> 2 waves/SIMD. Estimated need ~225 unified (acc 128 + frags 32 +
// staging 24 + addr ~40) -> fits WITHOUT spill (sentinel: WRITE_SIZE).
// Otherwise R9's verified pipeline verbatim: reg-staged (global->VGPR->
// swizzled ds_write, per-register vmcnt tracking keeps loads in flight across
// barriers), ONE lgkm-only barrier per BK=32 step, XOR swizzle (0 conflicts
// measured), swapped-operand MFMA, vectorized epilogue.
// LDS 48KB (A 2x16 + B 2x8). FLOP/LDS-byte = 29.1 vs R9's 21.3 (the lever).
// G1=true : hout = gelu(gather(x) @ B + bias)  [bf16]
// G1=false: hout = A @ B + bias                [fp16]
// ---------------------------------------------------------------------------
template<int KD, int ND, int NT, bool G1>
__global__ __launch_bounds__(256, 2) void gemm_mfma(
    const unsigned short* __restrict__ Abase,
    const unsigned short* __restrict__ Bt,
    const float* __restrict__ bias,
    const int* __restrict__ stok,
    const int* __restrict__ ecnt,
    unsigned short* __restrict__ hout)
{
    constexpr int ABUF = 256 * 32;            // 8192 elems = 16 KB per buf
    constexpr int BBUF = 128 * 32;            // 4096 elems =  8 KB per buf
    __shared__ __align__(16) unsigned short As[2 * ABUF];
    __shared__ __align__(16) unsigned short Bs[2 * BBUF];

    const int tid = threadIdx.x;
    const int e  = blockIdx.x & 7;            // expert == XCD (id%8 round-robin)
    const int g  = blockIdx.x >> 3;
    const int n0 = (g % NT) * 128;            // n fastest: reuse gathered A in L2
    const int m0 = (g / NT) * 256;

    if (m0 >= ecnt[e]) return;                // padding tile: skip

    const int lane = tid & 63;
    const int wid  = tid >> 6;

    // Staging: q = 16B chunk, r = base row. A rows r+{0,64,128,192}, B rows
    // r+{0,64}. XOR class (r>>1)&3 invariant under +64 -> one cSw for all.
    const int q = tid & 3;
    const int r = tid >> 2;                   // 0..63

    unsigned int aoff[4], boff[2];
#pragma unroll
    for (int i = 0; i < 4; i++) {
        unsigned int arow;
        if constexpr (G1) {
            const int t = stok[e * CAP + m0 + r + i * 64];
            arow = (unsigned int)(t >= 0 ? t : 0);   // dropped -> row 0
        } else {
            arow = (unsigned int)(e * CAP + m0 + r + i * 64);
        }
        aoff[i] = arow * KD + q * 8;
    }
#pragma unroll
    for (int i = 0; i < 2; i++)
        boff[i] = (unsigned int)((e * ND + n0 + r + i * 64) * KD) + q * 8;

    const int cSw = q ^ ((r >> 1) & 3);
    const int oW  = r * 32 + cSw * 8;         // +i*2048 folds into imm offset

    // Fragment read bases (R9-verified 0-conflict pattern).
    const int wm = wid >> 1, wn = wid & 1;    // wave tile: rows wm*128, cols wn*64
    const int l15  = lane & 15;
    const int quad = lane >> 4;
    const int xq   = quad ^ ((l15 >> 1) & 3);
    const int fA   = (wm * 128 + l15) * 32 + xq * 8;
    const int fB   = (wn * 64 + l15) * 32 + xq * 8;

    f32x4 acc[8][4];
#pragma unroll
    for (int i = 0; i < 8; i++)
#pragma unroll
        for (int j = 0; j < 4; j++) acc[i][j] = (f32x4)0.f;

// Swapped-operand MFMA: D = bfv x af -> col(lane&15) indexes m, row indexes n.
// Two half-phases reuse af[4] (peak frag regs 32, not 48 — R10 reg fix).
#define COMPUTE(PBUF)                                                          \
    {                                                                          \
        const unsigned short* Ab = As + (PBUF) * ABUF;                         \
        const unsigned short* Bb = Bs + (PBUF) * BBUF;                         \
        bf16x8 bfv[4], af[4];                                                  \
        _Pragma("unroll")                                                      \
        for (int j = 0; j < 4; j++) bfv[j] = *(const bf16x8*)(Bb + fB + j * 512); \
        _Pragma("unroll")                                                      \
        for (int i = 0; i < 4; i++) af[i]  = *(const bf16x8*)(Ab + fA + i * 512); \
        _Pragma("unroll")                                                      \
        for (int i = 0; i < 4; i++)                                            \
            _Pragma("unroll")                                                  \
            for (int j = 0; j < 4; j++)                                        \
                acc[i][j] = __builtin_amdgcn_mfma_f32_16x16x32_bf16(           \
                    bfv[j], af[i], acc[i][j], 0, 0, 0);                        \
        _Pragma("unroll")                                                      \
        for (int i = 0; i < 4; i++) af[i]  = *(const bf16x8*)(Ab + fA + (i + 4) * 512); \
        _Pragma("unroll")                                                      \
        for (int i = 0; i < 4; i++)                                            \
            _Pragma("unroll")                                                  \
            for (int j = 0; j < 4; j++)                                        \
                acc[i + 4][j] = __builtin_amdgcn_mfma_f32_16x16x32_bf16(       \
                    bfv[j], af[i], acc[i + 4][j], 0, 0, 0);                    \
    }

#define LOADT(KC)                                                              \
    {                                                                          \
        _Pragma("unroll")                                                      \
        for (int i = 0; i < 4; i++) ra[i] = *(const float4*)(Abase + aoff[i] + (KC)); \
        _Pragma("unroll")                                                      \
        for (int i = 0; i < 2; i++) rb[i] = *(const float4*)(Bt + boff[i] + (KC)); \
    }

#define WRITET(WB)                                                             \
    {                                                                          \
        _Pragma("unroll")                                                      \
        for (int i = 0; i < 4; i++) *(float4*)(&As[(WB) * ABUF + oW + i * 2048]) = ra[i]; \
        _Pragma("unroll")                                                      \
        for (int i = 0; i < 2; i++) *(float4*)(&Bs[(WB) * BBUF + oW + i * 2048]) = rb[i]; \
    }

// lgkm-only barrier: ds traffic ordered; in-flight global->reg loads survive.
#define LBAR asm volatile("s_waitcnt lgkmcnt(0)\n\ts_barrier" ::: "memory")

    float4 ra[4], rb[2];
    // Prologue: tile 0 -> regs -> buf0; tile 1 -> regs (in flight).
    LOADT(0);
    WRITET(0);
    LOADT(32);
    LBAR;

    int rbuf = 0;
    for (int kc = 0; kc < KD; kc += 32) {
        if (kc + 32 < KD) {
            WRITET(rbuf ^ 1);                 // vmcnt waits land here, precise
            if (kc + 64 < KD) LOADT(kc + 64);
        }
        COMPUTE(rbuf);
        LBAR;
        rbuf ^= 1;
    }
#undef COMPUTE
#undef LOADT
#undef WRITET
#undef LBAR

    // Epilogue (transposed D): m = wm*128 + i*16 + l15, n = wn*64 + j*16 +
    // quad*4 + g2 -> one ushort4 store per (i,j).
    float4 b4[4];
#pragma unroll
    for (int j = 0; j < 4; j++)
        b4[j] = *(const float4*)(bias + (size_t)e * ND + n0 + wn * 64 + j * 16 + quad * 4);
#pragma unroll
    for (int i = 0; i < 8; i++) {
        unsigned short* hrow = hout
            + ((size_t)e * CAP + m0 + wm * 128 + i * 16 + l15) * ND
            + n0 + wn * 64 + quad * 4;
#pragma unroll
        for (int j = 0; j < 4; j++) {
            const float v0 = acc[i][j][0] + b4[j].x;
            const float v1 = acc[i][j][1] + b4[j].y;
            const float v2 = acc[i][j][2] + b4[j].z;
            const float v3 = acc[i][j][3] + b4[j].w;
            ushort4 o;
            if constexpr (G1) {
                o.x = f2bf(gelu_fast(v0)); o.y = f2bf(gelu_fast(v1));
                o.z = f2bf(gelu_fast(v2)); o.w = f2bf(gelu_fast(v3));
            } else {
                o.x = f2h(v0); o.y = f2h(v1); o.z = f2h(v2); o.w = f2h(v3);
            }
            *(ushort4*)(hrow + j * 16) = o;
        }
    }
}

// ---------------------------------------------------------------------------
// Combine: out[t] = sum_k wgt[t,k] * eout[eidx[t,k], aslot[t,k]]
// ---------------------------------------------------------------------------
__global__ __launch_bounds__(256) void combine_kernel(
    const unsigned short* __restrict__ eout,
    const int* __restrict__ eidx, const int* __restrict__ aslot,
    const float* __restrict__ wgt, float* __restrict__ out)
{
    const int tid = threadIdx.x;
    const int t  = blockIdx.x * 2 + (tid >> 7);
    const int h0 = (tid & 127) * 4;
    float r0 = 0.f, r1 = 0.f, r2 = 0.f, r3 = 0.f;
#pragma unroll
    for (int k = 0; k < 2; k++) {
        const int a = t * 2 + k;
        const int s = aslot[a];
        if (s >= 0) {
            const float w = wgt[a];
            const int e = eidx[a];
            const ushort4 v = *(const ushort4*)(eout + ((size_t)e * CAP + s) * HD + h0);
            r0 += w * h2f(v.x); r1 += w * h2f(v.y);
            r2 += w * h2f(v.z); r3 += w * h2f(v.w);
        }
    }
    float4 o; o.x = r0; o.y = r1; o.z = r2; o.w = r3;
    *(float4*)(out + (size_t)t * HD + h0) = o;
}

extern "C" void kernel_launch(void* const* d_in, const int* in_sizes, int n_in,
                              void* d_out, int out_size, void* d_ws, size_t ws_size,
                              hipStream_t stream)
{
    const float* x  = (const float*)d_in[0];
    const float* rw = (const float*)d_in[1];
    const float* w1 = (const float*)d_in[2];
    const float* b1 = (const float*)d_in[3];
    const float* w2 = (const float*)d_in[4];
    const float* b2 = (const float*)d_in[5];
    float* out = (float*)d_out;

    char* ws = (char*)d_ws;
    int*   eidx  = (int*)  (ws + OFF_EIDX);
    float* wgt   = (float*)(ws + OFF_WGT);
    int*   stok  = (int*)  (ws + OFF_STOK);
    int*   aslot = (int*)  (ws + OFF_ASLOT);
    int*   ecnt  = (int*)  (ws + OFF_ECNT);
    unsigned short* w2t  = (unsigned short*)(ws + OFF_W2T);
    unsigned short* hbuf = (unsigned short*)(ws + OFF_H);
    unsigned short* w1t  = (unsigned short*)(ws + OFF_W1T);
    unsigned short* xbf  = (unsigned short*)(ws + OFF_XBF);
    unsigned short* eout = (unsigned short*)(ws + OFF_EOUT);

    transpose_cast_kernel<<<dim3(FD / 32, FD / 32, 2 * ED), 256, 0, stream>>>(
        w1, w1t, w2, w2t);
    router_kernel<<<NTOK / 4, 256, 0, stream>>>(x, rw, eidx, wgt, xbf);
    scan_kernel<<<1, 1024, 0, stream>>>(eidx, stok, aslot, ecnt);

    // GEMM1: h = gelu(gather(x) @ w1 + b1)  [bf16], 256x128 tiles
    gemm_mfma<HD, FD, FD/128, true>
        <<<8 * (FD/128) * (CAP/256), 256, 0, stream>>>(
        xbf, w1t, b1, stok, ecnt, hbuf);

    // GEMM2: eout = h @ w2 + b2  [fp16, per-slot], 256x128 tiles
    gemm_mfma<FD, HD, HD/128, false>
        <<<8 * (HD/128) * (CAP/256), 256, 0, stream>>>(
        hbuf, w2t, b2, nullptr, ecnt, eout);

    combine_kernel<<<NTOK / 2, 256, 0, stream>>>(eout, eidx, aslot, wgt, out);
}

// Round 12
// 454.880 us; speedup vs baseline: 2.0955x; 2.0955x over previous
//
#include <hip/hip_runtime.h>
#include <hip/hip_bf16.h>

// Problem constants (static per reference)
#define NTOK 16384   // B*T
#define HD   512     // H
#define ED   8       // E experts
#define FD   2048    // F
#define CAP  5120    // capacity per expert
#define NA   32768   // NTOK * K(=2)

typedef __bf16 bf16x8 __attribute__((ext_vector_type(8)));
typedef float  f32x4  __attribute__((ext_vector_type(4)));

// Workspace layout (bytes). Total ~249 MB.
static constexpr size_t OFF_EIDX = 0;                                  // int[NA]
static constexpr size_t OFF_WGT  = 131072;                             // float[NA]
static constexpr size_t OFF_STOK = 262144;                             // int[ED*CAP]
static constexpr size_t OFF_ASLOT= 425984;                             // int[NA]
static constexpr size_t OFF_ECNT = 557056;                             // int[ED]
static constexpr size_t OFF_W2T  = 1u << 20;                           // bf16[ED][HD][FD]
static constexpr size_t OFF_H    = OFF_W2T + (size_t)ED*HD*FD*2;       // bf16[ED][CAP][FD]
static constexpr size_t OFF_W1T  = OFF_H   + (size_t)ED*CAP*FD*2;      // bf16[ED][FD][HD]
static constexpr size_t OFF_XBF  = OFF_W1T + (size_t)ED*FD*HD*2;       // bf16[NTOK][HD]
static constexpr size_t OFF_EOUT = OFF_XBF + (size_t)NTOK*HD*2;        // fp16[ED][CAP][HD]

__device__ __forceinline__ unsigned short f2bf(float f) {
    __bf16 b = (__bf16)f;
    return __builtin_bit_cast(unsigned short, b);
}
__device__ __forceinline__ unsigned short f2h(float f) {
    _Float16 h = (_Float16)f;
    return __builtin_bit_cast(unsigned short, h);
}
__device__ __forceinline__ float h2f(unsigned short u) {
    return (float)__builtin_bit_cast(_Float16, u);
}

// gelu(tanh approx) == v * sigmoid(2*0.79788456*(v + 0.044715 v^3))
// rcp (~1ulp) instead of exact div: invisible after bf16 rounding (R2).
__device__ __forceinline__ float gelu_fast(float v) {
    const float t = v * v;
    const float u = v * fmaf(t, 0.0713548214f, 1.5957691216f);
    const float e = __expf(-u);
    return v * __builtin_amdgcn_rcpf(1.f + e);
}

// ---------------------------------------------------------------------------
// Fused weight transposes, zero-waste grid (64,16,16):
//  z <  ED: w1 [HD][FD] -> w1t [FD][HD]   (r0 = by*32 < HD, c0 = bx*32 < FD)
//  z >= ED: w2 [FD][HD] -> w2t [HD][FD]   (r0 = bx*32 < FD, c0 = by*32 < HD)
// (R10/R11-verified kernel body; grid waste removed by the index-role swap.)
// ---------------------------------------------------------------------------
__global__ __launch_bounds__(256) void transpose_cast_kernel(
    const float* __restrict__ w1, unsigned short* __restrict__ w1t,
    const float* __restrict__ w2, unsigned short* __restrict__ w2t)
{
    __shared__ unsigned short tile[32][33];
    const int z = blockIdx.z;
    const bool is1 = z < ED;
    const int e = is1 ? z : z - ED;
    const int R = is1 ? HD : FD;
    const int C = is1 ? FD : HD;
    const int r0 = (is1 ? blockIdx.y : blockIdx.x) * 32;
    const int c0 = (is1 ? blockIdx.x : blockIdx.y) * 32;
    const float* in = (is1 ? w1 : w2) + (size_t)e * HD * FD;
    unsigned short* out = (is1 ? w1t : w2t) + (size_t)e * HD * FD;
    const int tr = threadIdx.x >> 3, tc = (threadIdx.x & 7) * 4;
    const float4 v = *(const float4*)(in + (size_t)(r0 + tr) * C + c0 + tc);
    tile[tr][tc + 0] = f2bf(v.x);
    tile[tr][tc + 1] = f2bf(v.y);
    tile[tr][tc + 2] = f2bf(v.z);
    tile[tr][tc + 3] = f2bf(v.w);
    __syncthreads();
    ushort4 o;
    o.x = tile[tc + 0][tr]; o.y = tile[tc + 1][tr];
    o.z = tile[tc + 2][tr]; o.w = tile[tc + 3][tr];
    *(ushort4*)(out + (size_t)(c0 + tr) * R + r0 + tc) = o;
}

// ---------------------------------------------------------------------------
// Router (+ fused x->bf16 cast)
// ---------------------------------------------------------------------------
__global__ __launch_bounds__(256) void router_kernel(
    const float* __restrict__ x, const float* __restrict__ rw,
    int* __restrict__ eidx, float* __restrict__ wgt,
    unsigned short* __restrict__ xbf)
{
    __shared__ float rws[HD * ED];
    const int tid = threadIdx.x;
    for (int i = tid * 4; i < HD * ED; i += 256 * 4)
        *(float4*)(rws + i) = *(const float4*)(rw + i);
    __syncthreads();

    const int wid = tid >> 6, lane = tid & 63;
    const int t = blockIdx.x * 4 + wid;
    const float* xr = x + (size_t)t * HD;

    float acc[ED];
#pragma unroll
    for (int e = 0; e < ED; e++) acc[e] = 0.f;

    float4 xv0 = *(const float4*)(xr + lane * 8);
    float4 xv1 = *(const float4*)(xr + lane * 8 + 4);
    float xv[8] = {xv0.x, xv0.y, xv0.z, xv0.w, xv1.x, xv1.y, xv1.z, xv1.w};

    union { unsigned short us[8]; uint4 v; } pk;
#pragma unroll
    for (int j = 0; j < 8; j++) pk.us[j] = f2bf(xv[j]);
    *(uint4*)(xbf + (size_t)t * HD + lane * 8) = pk.v;

#pragma unroll
    for (int j = 0; j < 8; j++) {
        const int h = lane * 8 + j;
#pragma unroll
        for (int e = 0; e < ED; e++) acc[e] += xv[j] * rws[h * ED + e];
    }
#pragma unroll
    for (int off = 32; off >= 1; off >>= 1) {
#pragma unroll
        for (int e = 0; e < ED; e++) acc[e] += __shfl_down(acc[e], off);
    }
    if (lane == 0) {
        int e0 = 0; float l0 = acc[0];
        for (int e = 1; e < ED; e++) if (acc[e] > l0) { l0 = acc[e]; e0 = e; }
        int e1 = 0; float l1 = -1e30f;
        for (int e = 0; e < ED; e++) {
            if (e == e0) continue;
            if (acc[e] > l1) { l1 = acc[e]; e1 = e; }
        }
        const float ex = expf(l1 - l0);
        const float inv = 1.f / (1.f + ex);
        eidx[t * 2 + 0] = e0;  eidx[t * 2 + 1] = e1;
        wgt [t * 2 + 0] = inv; wgt [t * 2 + 1] = ex * inv;
    }
}

// ---------------------------------------------------------------------------
// Deterministic slot assignment (stable-sort-by-expert), parallel 3-pass scan.
// ---------------------------------------------------------------------------
__global__ __launch_bounds__(1024) void scan_kernel(
    const int* __restrict__ eidx,
    int* __restrict__ stok, int* __restrict__ aslot, int* __restrict__ ecnt)
{
    __shared__ int wcnt[32][16][ED];
    __shared__ int woff[32][16][ED];
    const int tid = threadIdx.x;
    const int lane = tid & 63, wid = tid >> 6;
    const unsigned long long below = (1ull << lane) - 1ull;

    for (int i = tid; i < ED * CAP; i += 1024) stok[i] = -1;

    for (int c = 0; c < NA / 1024; c++) {
        const int e = eidx[c * 1024 + tid];
#pragma unroll
        for (int ee = 0; ee < ED; ee++) {
            unsigned long long m = __ballot(e == ee);
            if (lane == 0) wcnt[c][wid][ee] = __popcll(m);
        }
    }
    __syncthreads();

    if (wid < ED) {
        const int e = wid;
        int carry = 0;
#pragma unroll
        for (int r = 0; r < 8; r++) {
            const int idx = r * 64 + lane;
            const int v = wcnt[idx >> 4][idx & 15][e];
            int s = v;
#pragma unroll
            for (int off = 1; off < 64; off <<= 1) {
                int u = __shfl_up(s, off);
                if (lane >= off) s += u;
            }
            woff[idx >> 4][idx & 15][e] = carry + s - v;
            carry += __shfl(s, 63);
        }
        if (lane == 0) ecnt[e] = carry < CAP ? carry : CAP;
    }
    __syncthreads();

    for (int c = 0; c < NA / 1024; c++) {
        const int a = c * 1024 + tid;
        const int e = eidx[a];
        int myrank = 0;
#pragma unroll
        for (int ee = 0; ee < ED; ee++) {
            unsigned long long m = __ballot(e == ee);
            if (ee == e) myrank = __popcll(m & below);
        }
        const int slot = woff[c][wid][e] + myrank;
        if (slot < CAP) {
            stok[e * CAP + slot] = a >> 1;
            aslot[a] = slot;
        } else {
            aslot[a] = -1;
        }
    }
}

// ---------------------------------------------------------------------------
// MFMA GEMM — R9's verified structure, reinstated verbatim (session best:
// 456 µs total, 132 µs/GEMM, MfmaUtil 22.7, 0 bank conflicts, no spill).
// Structure ledger (11 rounds of evidence):
//  * 128x128 block tile, 4 waves, 64x64 wave tile, BK=32;
//  * reg-staged staging (global->VGPR->swizzled ds_write): per-register vmcnt
//    tracking keeps loads in flight across barriers (gl_lds's conservative
//    alias-drain defeats counted vmcnt — R5 null, R8 regression);
//  * ONE lgkm-only barrier per K-step (no vmcnt drain);
//  * XOR swizzle: write LDS[r][q^((r>>1)&3)], read xq=quad^((l15>>1)&3) —
//    measured 0 conflicts;
//  * swapped-operand MFMA (D col->m): vectorized ushort4 epilogue;
//  * ecnt early-exit (~18% padding tiles skipped), exit pre-barrier;
//  * 3 waves/SIMD occupancy (88 VGPR + 64 acc); the 128x64-wave-tile ratio
//    lever is CLOSED at HIP level (R10: 272 regs -> 1 wave/SIMD; R11:
//    launch_bounds floor -> 390 MB scratch spill).
// G1=true : hout = gelu(gather(x) @ B + bias)  [bf16]
// G1=false: hout = A @ B + bias                [fp16]
// ---------------------------------------------------------------------------
template<int KD, int ND, int NT, bool G1>
__global__ __launch_bounds__(256) void gemm_mfma(
    const unsigned short* __restrict__ Abase,
    const unsigned short* __restrict__ Bt,
    const float* __restrict__ bias,
    const int* __restrict__ stok,
    const int* __restrict__ ecnt,
    unsigned short* __restrict__ hout)
{
    constexpr int BUFE = 128 * 32;            // 4096 elems = 8 KB per buf
    __shared__ __align__(16) unsigned short As[2 * BUFE];
    __shared__ __align__(16) unsigned short Bs[2 * BUFE];

    const int tid = threadIdx.x;
    const int e  = blockIdx.x & 7;            // expert == XCD (id%8 round-robin)
    const int g  = blockIdx.x >> 3;
    const int n0 = (g % NT) * 128;            // n fastest: reuse gathered A in L2
    const int m0 = (g / NT) * 128;

    if (m0 >= ecnt[e]) return;                // padding tile: exit pre-barrier

    const int lane = tid & 63;
    const int wid  = tid >> 6;

    // Staging: thread covers rows r1, r1+64; global 16B chunk q (coalesced).
    const int q  = tid & 3;
    const int r1 = tid >> 2;                  // 0..63
    const int r2 = r1 + 64;

    size_t ai1, ai2;
    if constexpr (G1) {
        const int t1 = stok[e * CAP + m0 + r1];
        const int t2 = stok[e * CAP + m0 + r2];
        ai1 = (size_t)(t1 >= 0 ? t1 : 0);     // dropped -> row 0 (never read back)
        ai2 = (size_t)(t2 >= 0 ? t2 : 0);
    } else {
        ai1 = (size_t)(e * CAP + m0 + r1);
        ai2 = (size_t)(e * CAP + m0 + r2);
    }
    const unsigned short* arow1 = Abase + ai1 * KD + q * 8;
    const unsigned short* arow2 = Abase + ai2 * KD + q * 8;
    const unsigned short* brow1 = Bt + ((size_t)e * ND + n0 + r1) * KD + q * 8;
    const unsigned short* brow2 = Bt + ((size_t)e * ND + n0 + r2) * KD + q * 8;

    // Swizzled ds_write offsets: LDS chunk c = q ^ ((r>>1)&3); same class for
    // r2 = r1+64. Write granule classes balanced (conflict-free).
    const int cSw = q ^ ((r1 >> 1) & 3);
    const int oW1 = r1 * 32 + cSw * 8;
    const int oW2 = r2 * 32 + cSw * 8;

    // Fragment read bases (verified 0-conflict): LDS[row][xq] = G[row][quad].
    const int wrow = (wid & 1) * 64;
    const int wcol = (wid >> 1) * 64;
    const int l15  = lane & 15;
    const int quad = lane >> 4;
    const int xq   = quad ^ ((l15 >> 1) & 3);
    const int fA   = (wrow + l15) * 32 + xq * 8;
    const int fB   = (wcol + l15) * 32 + xq * 8;

    f32x4 acc[4][4];
#pragma unroll
    for (int i = 0; i < 4; i++)
#pragma unroll
        for (int j = 0; j < 4; j++) acc[i][j] = (f32x4)0.f;

// Swapped-operand MFMA: D = bfv x af -> col(lane&15) indexes m, row indexes n.
#define COMPUTE(PBUF)                                                          \
    {                                                                          \
        const unsigned short* Ab = As + (PBUF) * BUFE;                         \
        const unsigned short* Bb = Bs + (PBUF) * BUFE;                         \
        bf16x8 af[4], bfv[4];                                                  \
        _Pragma("unroll")                                                      \
        for (int i = 0; i < 4; i++) af[i]  = *(const bf16x8*)(Ab + fA + i * 512); \
        _Pragma("unroll")                                                      \
        for (int j = 0; j < 4; j++) bfv[j] = *(const bf16x8*)(Bb + fB + j * 512); \
        _Pragma("unroll")                                                      \
        for (int i = 0; i < 4; i++)                                            \
            _Pragma("unroll")                                                  \
            for (int j = 0; j < 4; j++)                                        \
                acc[i][j] = __builtin_amdgcn_mfma_f32_16x16x32_bf16(           \
                    bfv[j], af[i], acc[i][j], 0, 0, 0);                        \
    }

// lgkm-only barrier: ds_writes visible + my ds_reads done; NO vmcnt drain —
// in-flight global->reg loads survive the barrier (per-register tracking).
#define LBAR asm volatile("s_waitcnt lgkmcnt(0)\n\ts_barrier" ::: "memory")

    // Prologue: tile 0 -> regs -> buf0; tile 1 -> regs (in flight).
    float4 ra1 = *(const float4*)(arow1);
    float4 ra2 = *(const float4*)(arow2);
    float4 rb1 = *(const float4*)(brow1);
    float4 rb2 = *(const float4*)(brow2);
    *(float4*)(&As[oW1]) = ra1;
    *(float4*)(&As[oW2]) = ra2;
    *(float4*)(&Bs[oW1]) = rb1;
    *(float4*)(&Bs[oW2]) = rb2;
    if (32 < KD) {
        ra1 = *(const float4*)(arow1 + 32);
        ra2 = *(const float4*)(arow2 + 32);
        rb1 = *(const float4*)(brow1 + 32);
        rb2 = *(const float4*)(brow2 + 32);
    }
    LBAR;

    int rbuf = 0;
    for (int kc = 0; kc < KD; kc += 32) {
        const int wb = (rbuf ^ 1) * BUFE;
        if (kc + 32 < KD) {
            // ds_write tile kc+32 (vmcnt wait: loads issued one iteration ago)
            *(float4*)(&As[wb + oW1]) = ra1;
            *(float4*)(&As[wb + oW2]) = ra2;
            *(float4*)(&Bs[wb + oW1]) = rb1;
            *(float4*)(&Bs[wb + oW2]) = rb2;
            if (kc + 64 < KD) {
                ra1 = *(const float4*)(arow1 + kc + 64);
                ra2 = *(const float4*)(arow2 + kc + 64);
                rb1 = *(const float4*)(brow1 + kc + 64);
                rb2 = *(const float4*)(brow2 + kc + 64);
            }
        }
        COMPUTE(rbuf);
        LBAR;
        rbuf ^= 1;
    }
#undef COMPUTE
#undef LBAR

    // Epilogue (transposed D): m = wrow + i*16 + l15, n = wcol + j*16 + quad*4
    // + g2 -> 4 consecutive n per (i,j) -> one ushort4 store each.
#pragma unroll
    for (int i = 0; i < 4; i++) {
        unsigned short* hrow = hout
            + ((size_t)e * CAP + m0 + wrow + i * 16 + l15) * ND
            + n0 + wcol + quad * 4;
#pragma unroll
        for (int j = 0; j < 4; j++) {
            const float4 b4 = *(const float4*)(
                bias + (size_t)e * ND + n0 + wcol + j * 16 + quad * 4);
            const float v0 = acc[i][j][0] + b4.x;
            const float v1 = acc[i][j][1] + b4.y;
            const float v2 = acc[i][j][2] + b4.z;
            const float v3 = acc[i][j][3] + b4.w;
            ushort4 o;
            if constexpr (G1) {
                o.x = f2bf(gelu_fast(v0)); o.y = f2bf(gelu_fast(v1));
                o.z = f2bf(gelu_fast(v2)); o.w = f2bf(gelu_fast(v3));
            } else {
                o.x = f2h(v0); o.y = f2h(v1); o.z = f2h(v2); o.w = f2h(v3);
            }
            *(ushort4*)(hrow + j * 16) = o;
        }
    }
}

// ---------------------------------------------------------------------------
// Combine: out[t] = sum_k wgt[t,k] * eout[eidx[t,k], aslot[t,k]]
// ---------------------------------------------------------------------------
__global__ __launch_bounds__(256) void combine_kernel(
    const unsigned short* __restrict__ eout,
    const int* __restrict__ eidx, const int* __restrict__ aslot,
    const float* __restrict__ wgt, float* __restrict__ out)
{
    const int tid = threadIdx.x;
    const int t  = blockIdx.x * 2 + (tid >> 7);
    const int h0 = (tid & 127) * 4;
    float r0 = 0.f, r1 = 0.f, r2 = 0.f, r3 = 0.f;
#pragma unroll
    for (int k = 0; k < 2; k++) {
        const int a = t * 2 + k;
        const int s = aslot[a];
        if (s >= 0) {
            const float w = wgt[a];
            const int e = eidx[a];
            const ushort4 v = *(const ushort4*)(eout + ((size_t)e * CAP + s) * HD + h0);
            r0 += w * h2f(v.x); r1 += w * h2f(v.y);
            r2 += w * h2f(v.z); r3 += w * h2f(v.w);
        }
    }
    float4 o; o.x = r0; o.y = r1; o.z = r2; o.w = r3;
    *(float4*)(out + (size_t)t * HD + h0) = o;
}

extern "C" void kernel_launch(void* const* d_in, const int* in_sizes, int n_in,
                              void* d_out, int out_size, void* d_ws, size_t ws_size,
                              hipStream_t stream)
{
    const float* x  = (const float*)d_in[0];
    const float* rw = (const float*)d_in[1];
    const float* w1 = (const float*)d_in[2];
    const float* b1 = (const float*)d_in[3];
    const float* w2 = (const float*)d_in[4];
    const float* b2 = (const float*)d_in[5];
    float* out = (float*)d_out;

    char* ws = (char*)d_ws;
    int*   eidx  = (int*)  (ws + OFF_EIDX);
    float* wgt   = (float*)(ws + OFF_WGT);
    int*   stok  = (int*)  (ws + OFF_STOK);
    int*   aslot = (int*)  (ws + OFF_ASLOT);
    int*   ecnt  = (int*)  (ws + OFF_ECNT);
    unsigned short* w2t  = (unsigned short*)(ws + OFF_W2T);
    unsigned short* hbuf = (unsigned short*)(ws + OFF_H);
    unsigned short* w1t  = (unsigned short*)(ws + OFF_W1T);
    unsigned short* xbf  = (unsigned short*)(ws + OFF_XBF);
    unsigned short* eout = (unsigned short*)(ws + OFF_EOUT);

    // Both weight transposes in one zero-waste launch:
    // z<8: w1 (y=HD/32=16 rows, x=FD/32=64 cols); z>=8: w2 (roles swapped).
    transpose_cast_kernel<<<dim3(FD / 32, HD / 32, 2 * ED), 256, 0, stream>>>(
        w1, w1t, w2, w2t);
    router_kernel<<<NTOK / 4, 256, 0, stream>>>(x, rw, eidx, wgt, xbf);
    scan_kernel<<<1, 1024, 0, stream>>>(eidx, stok, aslot, ecnt);

    // GEMM1: h = gelu(gather(x) @ w1 + b1)  [bf16], 128^2 tiles
    gemm_mfma<HD, FD, FD/128, true>
        <<<8 * (FD/128) * (CAP/128), 256, 0, stream>>>(
        xbf, w1t, b1, stok, ecnt, hbuf);

    // GEMM2: eout = h @ w2 + b2  [fp16, per-slot], 128^2 tiles
    gemm_mfma<FD, HD, HD/128, false>
        <<<8 * (HD/128) * (CAP/128), 256, 0, stream>>>(
        hbuf, w2t, b2, nullptr, ecnt, eout);

    combine_kernel<<<NTOK / 2, 256, 0, stream>>>(eout, eidx, aslot, wgt, out);
}

// Round 13
// 423.927 us; speedup vs baseline: 2.2485x; 1.0730x over previous
//
#include <hip/hip_runtime.h>
#include <hip/hip_bf16.h>

// Problem constants (static per reference)
#define NTOK 16384   // B*T
#define HD   512     // H
#define ED   8       // E experts
#define FD   2048    // F
#define CAP  5120    // capacity per expert
#define NA   32768   // NTOK * K(=2)

typedef __bf16 bf16x8 __attribute__((ext_vector_type(8)));
typedef float  f32x4  __attribute__((ext_vector_type(4)));

// Workspace layout (bytes). Total ~261 MB (verified fits: R9/R12 passed).
static constexpr size_t OFF_EIDX = 0;                                  // int[NA]
static constexpr size_t OFF_WGT  = 131072;                             // float[NA]
static constexpr size_t OFF_STOK = 262144;                             // int[ED*CAP]
static constexpr size_t OFF_ASLOT= 425984;                             // int[NA]
static constexpr size_t OFF_ECNT = 557056;                             // int[ED]
static constexpr size_t OFF_GWC  = 565248;                             // int[32][16][ED] counts
static constexpr size_t OFF_GWO  = 581632;                             // int[32][16][ED] offsets
static constexpr size_t OFF_W2T  = 1u << 20;                           // bf16[ED][HD][FD]
static constexpr size_t OFF_H    = OFF_W2T + (size_t)ED*HD*FD*2;       // bf16[ED][CAP][FD]
static constexpr size_t OFF_W1T  = OFF_H   + (size_t)ED*CAP*FD*2;      // bf16[ED][FD][HD]
static constexpr size_t OFF_XBF  = OFF_W1T + (size_t)ED*FD*HD*2;       // bf16[NTOK][HD]
static constexpr size_t OFF_EOUT = OFF_XBF + (size_t)NTOK*HD*2;        // fp16[ED][CAP][HD]

__device__ __forceinline__ unsigned short f2bf(float f) {
    __bf16 b = (__bf16)f;
    return __builtin_bit_cast(unsigned short, b);
}
__device__ __forceinline__ unsigned short f2h(float f) {
    _Float16 h = (_Float16)f;
    return __builtin_bit_cast(unsigned short, h);
}
__device__ __forceinline__ float h2f(unsigned short u) {
    return (float)__builtin_bit_cast(_Float16, u);
}

// gelu(tanh approx) == v * sigmoid(2*0.79788456*(v + 0.044715 v^3))
// rcp (~1ulp) instead of exact div: invisible after bf16 rounding (R2).
__device__ __forceinline__ float gelu_fast(float v) {
    const float t = v * v;
    const float u = v * fmaf(t, 0.0713548214f, 1.5957691216f);
    const float e = __expf(-u);
    return v * __builtin_amdgcn_rcpf(1.f + e);
}

// ---------------------------------------------------------------------------
// Fused prep: z<16 -> weight transpose (zero-waste role-swapped grid, R12-
// verified body); z>=16 -> router (+x->bf16 cast), block b=(z-16)*1024+by*64+bx.
// One launch instead of two (fewer graph-node gaps).
// ---------------------------------------------------------------------------
__global__ __launch_bounds__(256) void prep_kernel(
    const float* __restrict__ w1, unsigned short* __restrict__ w1t,
    const float* __restrict__ w2, unsigned short* __restrict__ w2t,
    const float* __restrict__ x,  const float* __restrict__ rw,
    int* __restrict__ eidx, float* __restrict__ wgt,
    unsigned short* __restrict__ xbf)
{
    const int z = blockIdx.z;
    const int tid = threadIdx.x;

    if (z < 2 * ED) {
        // ---- weight transpose: [R][C] fp32 -> [C][R] bf16 per expert ----
        __shared__ unsigned short tile[32][33];
        const bool is1 = z < ED;
        const int e = is1 ? z : z - ED;
        const int R = is1 ? HD : FD;
        const int C = is1 ? FD : HD;
        const int r0 = (is1 ? blockIdx.y : blockIdx.x) * 32;
        const int c0 = (is1 ? blockIdx.x : blockIdx.y) * 32;
        const float* in = (is1 ? w1 : w2) + (size_t)e * HD * FD;
        unsigned short* out = (is1 ? w1t : w2t) + (size_t)e * HD * FD;
        const int tr = tid >> 3, tc = (tid & 7) * 4;
        const float4 v = *(const float4*)(in + (size_t)(r0 + tr) * C + c0 + tc);
        tile[tr][tc + 0] = f2bf(v.x);
        tile[tr][tc + 1] = f2bf(v.y);
        tile[tr][tc + 2] = f2bf(v.z);
        tile[tr][tc + 3] = f2bf(v.w);
        __syncthreads();
        ushort4 o;
        o.x = tile[tc + 0][tr]; o.y = tile[tc + 1][tr];
        o.z = tile[tc + 2][tr]; o.w = tile[tc + 3][tr];
        *(ushort4*)(out + (size_t)(c0 + tr) * R + r0 + tc) = o;
        return;
    }

    // ---- router ----
    __shared__ float rws[HD * ED];
    for (int i = tid * 4; i < HD * ED; i += 256 * 4)
        *(float4*)(rws + i) = *(const float4*)(rw + i);
    __syncthreads();

    const int b = (z - 2 * ED) * 1024 + blockIdx.y * 64 + blockIdx.x;
    const int wid = tid >> 6, lane = tid & 63;
    const int t = b * 4 + wid;
    const float* xr = x + (size_t)t * HD;

    float acc[ED];
#pragma unroll
    for (int e = 0; e < ED; e++) acc[e] = 0.f;

    float4 xv0 = *(const float4*)(xr + lane * 8);
    float4 xv1 = *(const float4*)(xr + lane * 8 + 4);
    float xv[8] = {xv0.x, xv0.y, xv0.z, xv0.w, xv1.x, xv1.y, xv1.z, xv1.w};

    union { unsigned short us[8]; uint4 v; } pk;
#pragma unroll
    for (int j = 0; j < 8; j++) pk.us[j] = f2bf(xv[j]);
    *(uint4*)(xbf + (size_t)t * HD + lane * 8) = pk.v;

#pragma unroll
    for (int j = 0; j < 8; j++) {
        const int h = lane * 8 + j;
#pragma unroll
        for (int e = 0; e < ED; e++) acc[e] += xv[j] * rws[h * ED + e];
    }
#pragma unroll
    for (int off = 32; off >= 1; off >>= 1) {
#pragma unroll
        for (int e = 0; e < ED; e++) acc[e] += __shfl_down(acc[e], off);
    }
    if (lane == 0) {
        int e0 = 0; float l0 = acc[0];
        for (int e = 1; e < ED; e++) if (acc[e] > l0) { l0 = acc[e]; e0 = e; }
        int e1 = 0; float l1 = -1e30f;
        for (int e = 0; e < ED; e++) {
            if (e == e0) continue;
            if (acc[e] > l1) { l1 = acc[e]; e1 = e; }
        }
        const float ex = expf(l1 - l0);
        const float inv = 1.f / (1.f + ex);
        eidx[t * 2 + 0] = e0;  eidx[t * 2 + 1] = e1;
        wgt [t * 2 + 0] = inv; wgt [t * 2 + 1] = ex * inv;
    }
}

// ---------------------------------------------------------------------------
// Wide 3-phase scan (R12 post-mortem: the 1-block scan serialized two
// 32-chunk global-latency passes on ONE CU while 255 idled). Identical math
// and assignment order (chunk c, wave w, lane rank) -> identical stable
// deterministic slots.
// Phase 1 (32 blocks): per-(chunk,wave,expert) ballot counts -> gwcnt; also
//                      stok = -1 init.
// Phase 2 (1 tiny block, 8 waves): per-expert exclusive prefix over the 512
//                      (c,w) entries -> gwoff, ecnt.
// Phase 3 (32 blocks): recompute wave ballots, slot = gwoff + myrank.
// ---------------------------------------------------------------------------
__global__ __launch_bounds__(1024) void scan_count_kernel(
    const int* __restrict__ eidx, int* __restrict__ gwcnt,
    int* __restrict__ stok)
{
    const int c = blockIdx.x;
    const int tid = threadIdx.x;
    const int lane = tid & 63, wid = tid >> 6;

    // stok init: 32 blocks x 1024 threads cover ED*CAP = 40960
    for (int i = c * 1024 + tid; i < ED * CAP; i += 32 * 1024) stok[i] = -1;

    const int e = eidx[c * 1024 + tid];
#pragma unroll
    for (int ee = 0; ee < ED; ee++) {
        unsigned long long m = __ballot(e == ee);
        if (lane == 0) gwcnt[(c * 16 + wid) * ED + ee] = __popcll(m);
    }
}

__global__ __launch_bounds__(512) void scan_prefix_kernel(
    const int* __restrict__ gwcnt, int* __restrict__ gwoff,
    int* __restrict__ ecnt)
{
    const int tid = threadIdx.x;
    const int lane = tid & 63, wid = tid >> 6;
    const int e = wid;                        // 8 waves, one expert each
    int carry = 0;
#pragma unroll
    for (int r = 0; r < 8; r++) {
        const int idx = r * 64 + lane;        // (c,w) linear: matches assign order
        const int v = gwcnt[idx * ED + e];
        int s = v;
#pragma unroll
        for (int off = 1; off < 64; off <<= 1) {
            int u = __shfl_up(s, off);
            if (lane >= off) s += u;
        }
        gwoff[idx * ED + e] = carry + s - v;
        carry += __shfl(s, 63);
    }
    if (lane == 0) ecnt[e] = carry < CAP ? carry : CAP;
}

__global__ __launch_bounds__(1024) void scan_assign_kernel(
    const int* __restrict__ eidx, const int* __restrict__ gwoff,
    int* __restrict__ stok, int* __restrict__ aslot)
{
    const int c = blockIdx.x;
    const int tid = threadIdx.x;
    const int lane = tid & 63, wid = tid >> 6;
    const unsigned long long below = (1ull << lane) - 1ull;

    const int a = c * 1024 + tid;
    const int e = eidx[a];
    int myrank = 0;
#pragma unroll
    for (int ee = 0; ee < ED; ee++) {
        unsigned long long m = __ballot(e == ee);
        if (ee == e) myrank = __popcll(m & below);
    }
    const int slot = gwoff[(c * 16 + wid) * ED + e] + myrank;
    if (slot < CAP) {
        stok[e * CAP + slot] = a >> 1;        // token = a / K
        aslot[a] = slot;
    } else {
        aslot[a] = -1;                        // dropped
    }
}

// ---------------------------------------------------------------------------
// MFMA GEMM — R9/R12-verified structure (untouched; session best). Model now
// CLOSED: both GEMMs measure 1200 cyc per CU-K-step = 3 resident blocks x
// 48 KB LDS traffic / 1200 cyc = 122 B/cyc ~= 95% of the 128 B/cyc LDS port.
// This structure is LDS-port-roofline-bound; escapes evidenced closed:
// ratio lever (R10: 272 regs -> 1 wave/SIMD; R11: lb-floor -> 390 MB spill),
// DMA staging (R5 null / R8 regression: compiler alias-drain), L2-direct B
// (60 B/cyc/CU L2 share < demand), fp8 (tolerance).
// G1=true : hout = gelu(gather(x) @ B + bias)  [bf16]
// G1=false: hout = A @ B + bias                [fp16]
// ---------------------------------------------------------------------------
template<int KD, int ND, int NT, bool G1>
__global__ __launch_bounds__(256) void gemm_mfma(
    const unsigned short* __restrict__ Abase,
    const unsigned short* __restrict__ Bt,
    const float* __restrict__ bias,
    const int* __restrict__ stok,
    const int* __restrict__ ecnt,
    unsigned short* __restrict__ hout)
{
    constexpr int BUFE = 128 * 32;            // 4096 elems = 8 KB per buf
    __shared__ __align__(16) unsigned short As[2 * BUFE];
    __shared__ __align__(16) unsigned short Bs[2 * BUFE];

    const int tid = threadIdx.x;
    const int e  = blockIdx.x & 7;            // expert == XCD (id%8 round-robin)
    const int g  = blockIdx.x >> 3;
    const int n0 = (g % NT) * 128;            // n fastest: reuse gathered A in L2
    const int m0 = (g / NT) * 128;

    if (m0 >= ecnt[e]) return;                // padding tile: exit pre-barrier

    const int lane = tid & 63;
    const int wid  = tid >> 6;

    // Staging: thread covers rows r1, r1+64; global 16B chunk q (coalesced).
    const int q  = tid & 3;
    const int r1 = tid >> 2;                  // 0..63
    const int r2 = r1 + 64;

    size_t ai1, ai2;
    if constexpr (G1) {
        const int t1 = stok[e * CAP + m0 + r1];
        const int t2 = stok[e * CAP + m0 + r2];
        ai1 = (size_t)(t1 >= 0 ? t1 : 0);     // dropped -> row 0 (never read back)
        ai2 = (size_t)(t2 >= 0 ? t2 : 0);
    } else {
        ai1 = (size_t)(e * CAP + m0 + r1);
        ai2 = (size_t)(e * CAP + m0 + r2);
    }
    const unsigned short* arow1 = Abase + ai1 * KD + q * 8;
    const unsigned short* arow2 = Abase + ai2 * KD + q * 8;
    const unsigned short* brow1 = Bt + ((size_t)e * ND + n0 + r1) * KD + q * 8;
    const unsigned short* brow2 = Bt + ((size_t)e * ND + n0 + r2) * KD + q * 8;

    // Swizzled ds_write offsets: LDS chunk c = q ^ ((r>>1)&3); same class for
    // r2 = r1+64. Write granule classes balanced (conflict-free).
    const int cSw = q ^ ((r1 >> 1) & 3);
    const int oW1 = r1 * 32 + cSw * 8;
    const int oW2 = r2 * 32 + cSw * 8;

    // Fragment read bases (verified 0-conflict): LDS[row][xq] = G[row][quad].
    const int wrow = (wid & 1) * 64;
    const int wcol = (wid >> 1) * 64;
    const int l15  = lane & 15;
    const int quad = lane >> 4;
    const int xq   = quad ^ ((l15 >> 1) & 3);
    const int fA   = (wrow + l15) * 32 + xq * 8;
    const int fB   = (wcol + l15) * 32 + xq * 8;

    f32x4 acc[4][4];
#pragma unroll
    for (int i = 0; i < 4; i++)
#pragma unroll
        for (int j = 0; j < 4; j++) acc[i][j] = (f32x4)0.f;

// Swapped-operand MFMA: D = bfv x af -> col(lane&15) indexes m, row indexes n.
#define COMPUTE(PBUF)                                                          \
    {                                                                          \
        const unsigned short* Ab = As + (PBUF) * BUFE;                         \
        const unsigned short* Bb = Bs + (PBUF) * BUFE;                         \
        bf16x8 af[4], bfv[4];                                                  \
        _Pragma("unroll")                                                      \
        for (int i = 0; i < 4; i++) af[i]  = *(const bf16x8*)(Ab + fA + i * 512); \
        _Pragma("unroll")                                                      \
        for (int j = 0; j < 4; j++) bfv[j] = *(const bf16x8*)(Bb + fB + j * 512); \
        _Pragma("unroll")                                                      \
        for (int i = 0; i < 4; i++)                                            \
            _Pragma("unroll")                                                  \
            for (int j = 0; j < 4; j++)                                        \
                acc[i][j] = __builtin_amdgcn_mfma_f32_16x16x32_bf16(           \
                    bfv[j], af[i], acc[i][j], 0, 0, 0);                        \
    }

// lgkm-only barrier: ds_writes visible + my ds_reads done; NO vmcnt drain —
// in-flight global->reg loads survive the barrier (per-register tracking).
#define LBAR asm volatile("s_waitcnt lgkmcnt(0)\n\ts_barrier" ::: "memory")

    // Prologue: tile 0 -> regs -> buf0; tile 1 -> regs (in flight).
    float4 ra1 = *(const float4*)(arow1);
    float4 ra2 = *(const float4*)(arow2);
    float4 rb1 = *(const float4*)(brow1);
    float4 rb2 = *(const float4*)(brow2);
    *(float4*)(&As[oW1]) = ra1;
    *(float4*)(&As[oW2]) = ra2;
    *(float4*)(&Bs[oW1]) = rb1;
    *(float4*)(&Bs[oW2]) = rb2;
    if (32 < KD) {
        ra1 = *(const float4*)(arow1 + 32);
        ra2 = *(const float4*)(arow2 + 32);
        rb1 = *(const float4*)(brow1 + 32);
        rb2 = *(const float4*)(brow2 + 32);
    }
    LBAR;

    int rbuf = 0;
    for (int kc = 0; kc < KD; kc += 32) {
        const int wb = (rbuf ^ 1) * BUFE;
        if (kc + 32 < KD) {
            // ds_write tile kc+32 (vmcnt wait: loads issued one iteration ago)
            *(float4*)(&As[wb + oW1]) = ra1;
            *(float4*)(&As[wb + oW2]) = ra2;
            *(float4*)(&Bs[wb + oW1]) = rb1;
            *(float4*)(&Bs[wb + oW2]) = rb2;
            if (kc + 64 < KD) {
                ra1 = *(const float4*)(arow1 + kc + 64);
                ra2 = *(const float4*)(arow2 + kc + 64);
                rb1 = *(const float4*)(brow1 + kc + 64);
                rb2 = *(const float4*)(brow2 + kc + 64);
            }
        }
        COMPUTE(rbuf);
        LBAR;
        rbuf ^= 1;
    }
#undef COMPUTE
#undef LBAR

    // Epilogue (transposed D): m = wrow + i*16 + l15, n = wcol + j*16 + quad*4
    // + g2 -> 4 consecutive n per (i,j) -> one ushort4 store each.
#pragma unroll
    for (int i = 0; i < 4; i++) {
        unsigned short* hrow = hout
            + ((size_t)e * CAP + m0 + wrow + i * 16 + l15) * ND
            + n0 + wcol + quad * 4;
#pragma unroll
        for (int j = 0; j < 4; j++) {
            const float4 b4 = *(const float4*)(
                bias + (size_t)e * ND + n0 + wcol + j * 16 + quad * 4);
            const float v0 = acc[i][j][0] + b4.x;
            const float v1 = acc[i][j][1] + b4.y;
            const float v2 = acc[i][j][2] + b4.z;
            const float v3 = acc[i][j][3] + b4.w;
            ushort4 o;
            if constexpr (G1) {
                o.x = f2bf(gelu_fast(v0)); o.y = f2bf(gelu_fast(v1));
                o.z = f2bf(gelu_fast(v2)); o.w = f2bf(gelu_fast(v3));
            } else {
                o.x = f2h(v0); o.y = f2h(v1); o.z = f2h(v2); o.w = f2h(v3);
            }
            *(ushort4*)(hrow + j * 16) = o;
        }
    }
}

// ---------------------------------------------------------------------------
// Combine: out[t] = sum_k wgt[t,k] * eout[eidx[t,k], aslot[t,k]]
// ---------------------------------------------------------------------------
__global__ __launch_bounds__(256) void combine_kernel(
    const unsigned short* __restrict__ eout,
    const int* __restrict__ eidx, const int* __restrict__ aslot,
    const float* __restrict__ wgt, float* __restrict__ out)
{
    const int tid = threadIdx.x;
    const int t  = blockIdx.x * 2 + (tid >> 7);
    const int h0 = (tid & 127) * 4;
    float r0 = 0.f, r1 = 0.f, r2 = 0.f, r3 = 0.f;
#pragma unroll
    for (int k = 0; k < 2; k++) {
        const int a = t * 2 + k;
        const int s = aslot[a];
        if (s >= 0) {
            const float w = wgt[a];
            const int e = eidx[a];
            const ushort4 v = *(const ushort4*)(eout + ((size_t)e * CAP + s) * HD + h0);
            r0 += w * h2f(v.x); r1 += w * h2f(v.y);
            r2 += w * h2f(v.z); r3 += w * h2f(v.w);
        }
    }
    float4 o; o.x = r0; o.y = r1; o.z = r2; o.w = r3;
    *(float4*)(out + (size_t)t * HD + h0) = o;
}

extern "C" void kernel_launch(void* const* d_in, const int* in_sizes, int n_in,
                              void* d_out, int out_size, void* d_ws, size_t ws_size,
                              hipStream_t stream)
{
    const float* x  = (const float*)d_in[0];
    const float* rw = (const float*)d_in[1];
    const float* w1 = (const float*)d_in[2];
    const float* b1 = (const float*)d_in[3];
    const float* w2 = (const float*)d_in[4];
    const float* b2 = (const float*)d_in[5];
    float* out = (float*)d_out;

    char* ws = (char*)d_ws;
    int*   eidx  = (int*)  (ws + OFF_EIDX);
    float* wgt   = (float*)(ws + OFF_WGT);
    int*   stok  = (int*)  (ws + OFF_STOK);
    int*   aslot = (int*)  (ws + OFF_ASLOT);
    int*   ecnt  = (int*)  (ws + OFF_ECNT);
    int*   gwcnt = (int*)  (ws + OFF_GWC);
    int*   gwoff = (int*)  (ws + OFF_GWO);
    unsigned short* w2t  = (unsigned short*)(ws + OFF_W2T);
    unsigned short* hbuf = (unsigned short*)(ws + OFF_H);
    unsigned short* w1t  = (unsigned short*)(ws + OFF_W1T);
    unsigned short* xbf  = (unsigned short*)(ws + OFF_XBF);
    unsigned short* eout = (unsigned short*)(ws + OFF_EOUT);

    // Prep: weight transposes (z<16) + router (z>=16) in ONE launch.
    prep_kernel<<<dim3(64, 16, 2 * ED + 4), 256, 0, stream>>>(
        w1, w1t, w2, w2t, x, rw, eidx, wgt, xbf);

    // Wide deterministic scan: counts -> prefix -> assign.
    scan_count_kernel <<<32, 1024, 0, stream>>>(eidx, gwcnt, stok);
    scan_prefix_kernel<<<1, 512, 0, stream>>>(gwcnt, gwoff, ecnt);
    scan_assign_kernel<<<32, 1024, 0, stream>>>(eidx, gwoff, stok, aslot);

    // GEMM1: h = gelu(gather(x) @ w1 + b1)  [bf16], 128^2 tiles
    gemm_mfma<HD, FD, FD/128, true>
        <<<8 * (FD/128) * (CAP/128), 256, 0, stream>>>(
        xbf, w1t, b1, stok, ecnt, hbuf);

    // GEMM2: eout = h @ w2 + b2  [fp16, per-slot], 128^2 tiles
    gemm_mfma<FD, HD, HD/128, false>
        <<<8 * (HD/128) * (CAP/128), 256, 0, stream>>>(
        hbuf, w2t, b2, nullptr, ecnt, eout);

    combine_kernel<<<NTOK / 2, 256, 0, stream>>>(eout, eidx, aslot, wgt, out);
}